// Round 4
// baseline (129.624 us; speedup 1.0000x reference)
//
#include <hip/hip_runtime.h>

#define D_SAMPLE 256
#define KCLIENTS 64
#define NH 128      // hidden dim
#define STAGE_P 8   // client rows prefetched into LDS before the spin
#define BLOCK 256

// d_ws layout: byte 0: int counter (memset to 0 each call); byte 256: float scores[64]
__global__ __launch_bounds__(BLOCK, 4)
void lf_onekernel(const float* __restrict__ client,
                  const float* __restrict__ globalt,
                  const float* __restrict__ W1,
                  const float* __restrict__ b1,
                  const float* __restrict__ W2,
                  const float* __restrict__ b2,
                  int* __restrict__ counter,
                  float* __restrict__ scores,
                  float* __restrict__ out,
                  int D, int D4) {
    __shared__ float4 stage[STAGE_P][BLOCK];   // 32 KB
    __shared__ float  attn[2 * D_SAMPLE];      // 2 KB
    __shared__ float  ph[2][NH];               // 1 KB
    __shared__ float  red[2];
    __shared__ float  w[KCLIENTS];

    const int t = threadIdx.x;
    const int b = blockIdx.x;
    const float4* __restrict__ c4 = (const float4*)client;
    const float4* __restrict__ g4 = (const float4*)globalt;
    float4* __restrict__ o4 = (float4*)out;

    const int  d      = b * BLOCK + t;
    const bool active = (d < D4);

    // ============ Phase 1 (blocks 0..63): score for client k = b ============
    if (b < KCLIENTS) {
        const int k = b;
        attn[t]            = client[(size_t)k * D + t];
        attn[D_SAMPLE + t] = globalt[t];
        __syncthreads();

        const int q = t >> 7;        // which half of the 512 inputs
        const int j = t & (NH - 1);  // hidden unit
        const float* __restrict__ w1p = W1 + (size_t)(q * D_SAMPLE) * NH + j;
        const float* __restrict__ xp  = attn + q * D_SAMPLE;

        float a0 = 0.f, a1 = 0.f;
#pragma unroll 8
        for (int i = 0; i < D_SAMPLE; i += 2) {
            a0 = fmaf(xp[i],     w1p[(size_t)i * NH],       a0);
            a1 = fmaf(xp[i + 1], w1p[(size_t)(i + 1) * NH], a1);
        }
        ph[q][j] = a0 + a1;
        __syncthreads();

        if (t < NH) {
            float h = b1[j] + ph[0][j] + ph[1][j];
            h = fmaxf(h, 0.0f);
            float v = h * W2[j];
#pragma unroll
            for (int off = 32; off > 0; off >>= 1)
                v += __shfl_down(v, off, 64);
            if ((t & 63) == 0) red[t >> 6] = v;
        }
        __syncthreads();
        if (t == 0) {
            float s = red[0] + red[1] + b2[0];
            __hip_atomic_store(&scores[k], s, __ATOMIC_RELAXED, __HIP_MEMORY_SCOPE_AGENT);
            __hip_atomic_fetch_add(counter, 1, __ATOMIC_RELEASE, __HIP_MEMORY_SCOPE_AGENT);
        }
    }

    // ============ All blocks: prefetch STAGE_P rows while scores finish ============
#pragma unroll
    for (int k = 0; k < STAGE_P; ++k) {
        float4 v = make_float4(0.f, 0.f, 0.f, 0.f);
        if (active) v = c4[(size_t)k * D4 + d];
        stage[k][t] = v;
    }

    // ============ Wait for all 64 scores (one-way, acquire) ============
    if (t == 0) {
        while (__hip_atomic_load(counter, __ATOMIC_ACQUIRE, __HIP_MEMORY_SCOPE_AGENT)
               < KCLIENTS)
            __builtin_amdgcn_s_sleep(8);
    }
    __syncthreads();

    // ============ Per-block softmax over the 64 scores ============
    if (t < KCLIENTS) {
        float s = __hip_atomic_load(&scores[t], __ATOMIC_RELAXED, __HIP_MEMORY_SCOPE_AGENT);
        float m = s;
#pragma unroll
        for (int off = 32; off > 0; off >>= 1)
            m = fmaxf(m, __shfl_xor(m, off, 64));
        float e = __expf(s - m);
        float sum = e;
#pragma unroll
        for (int off = 32; off > 0; off >>= 1)
            sum += __shfl_xor(sum, off, 64);
        w[t] = e / sum;
    }
    __syncthreads();

    // ============ Fuse ============
    if (active) {
        float4 acc = make_float4(0.f, 0.f, 0.f, 0.f);
#pragma unroll
        for (int k = 0; k < STAGE_P; ++k) {
            const float wk = w[k];
            const float4 c = stage[k][t];
            acc.x = fmaf(wk, c.x, acc.x);
            acc.y = fmaf(wk, c.y, acc.y);
            acc.z = fmaf(wk, c.z, acc.z);
            acc.w = fmaf(wk, c.w, acc.w);
        }
#pragma unroll 8
        for (int k = STAGE_P; k < KCLIENTS; ++k) {
            const float wk = w[k];
            const float4 c = c4[(size_t)k * D4 + d];
            acc.x = fmaf(wk, c.x, acc.x);
            acc.y = fmaf(wk, c.y, acc.y);
            acc.z = fmaf(wk, c.z, acc.z);
            acc.w = fmaf(wk, c.w, acc.w);
        }
        const float4 g = g4[d];
        float4 r;
        r.x = 0.5f * g.x + 0.5f * acc.x;
        r.y = 0.5f * g.y + 0.5f * acc.y;
        r.z = 0.5f * g.z + 0.5f * acc.z;
        r.w = 0.5f * g.w + 0.5f * acc.w;
        o4[d] = r;
    }
}

extern "C" void kernel_launch(void* const* d_in, const int* in_sizes, int n_in,
                              void* d_out, int out_size, void* d_ws, size_t ws_size,
                              hipStream_t stream) {
    const float* client  = (const float*)d_in[0];  // [64, D]
    const float* globalt = (const float*)d_in[1];  // [1, D]
    const float* W1      = (const float*)d_in[2];  // [512, 128]
    const float* b1      = (const float*)d_in[3];  // [128]
    const float* W2      = (const float*)d_in[4];  // [128, 1]
    const float* b2      = (const float*)d_in[5];  // [1]
    float* out = (float*)d_out;                    // [1, D]

    int D  = in_sizes[0] / KCLIENTS;               // 1,000,000
    int D4 = D / 4;                                // 250,000

    int*   counter = (int*)d_ws;                       // byte 0
    float* scores  = (float*)((char*)d_ws + 256);      // byte 256

    // reset the producer-consumer counter each call (graph-capture legal)
    hipMemsetAsync(d_ws, 0, 256, stream);

    int grid = (D4 + BLOCK - 1) / BLOCK;           // 977 blocks <= 1024 co-resident
    lf_onekernel<<<grid, BLOCK, 0, stream>>>(client, globalt, W1, b1, W2, b2,
                                             counter, scores, out, D, D4);
}

// Round 6
// 47.619 us; speedup vs baseline: 2.7221x; 2.7221x over previous
//
#include <hip/hip_runtime.h>

#define D_SAMPLE 256
#define KCLIENTS 64
#define NH 128     // hidden dim
#define PF 8       // fuse: rows prefetched to registers before softmax
#define BLOCK 256

typedef float vfloat4 __attribute__((ext_vector_type(4)));

// ---------------- Kernel 1: per-client attention scores ----------------
// grid = 64 blocks (one per client k), block = 1024 threads:
// t -> (q = t>>7: one of 8 i-slices of the 512 inputs, j = t&127: hidden unit).
// Each thread: 64 FMAs over its slice; 8 partials combined in LDS.
__global__ __launch_bounds__(1024)
void lf_scores_kernel(const float* __restrict__ client,
                      const float* __restrict__ globalt,
                      const float* __restrict__ W1,
                      const float* __restrict__ b1,
                      const float* __restrict__ W2,
                      const float* __restrict__ b2,
                      float* __restrict__ scores,
                      int D) {
    const int k = blockIdx.x;
    const int t = threadIdx.x;   // 0..1023

    __shared__ float attn[2 * D_SAMPLE];   // [client samples | global samples]
    __shared__ float ph[8][NH];
    __shared__ float red[2];

    if (t < D_SAMPLE)            attn[t] = client[(size_t)k * D + t];
    else if (t < 2 * D_SAMPLE)   attn[t] = globalt[t - D_SAMPLE];
    __syncthreads();

    const int q = t >> 7;        // i-slice 0..7 (64 inputs each)
    const int j = t & (NH - 1);  // hidden unit
    const float* __restrict__ w1p = W1 + (size_t)(q * 64) * NH + j;
    const float* __restrict__ xp  = attn + q * 64;

    float a0 = 0.f, a1 = 0.f;
#pragma unroll 8
    for (int i = 0; i < 64; i += 2) {
        a0 = fmaf(xp[i],     w1p[(size_t)i * NH],       a0);
        a1 = fmaf(xp[i + 1], w1p[(size_t)(i + 1) * NH], a1);
    }
    ph[q][j] = a0 + a1;
    __syncthreads();

    if (t < NH) {
        float h = b1[j];
#pragma unroll
        for (int r = 0; r < 8; ++r) h += ph[r][j];
        h = fmaxf(h, 0.0f);
        float v = h * W2[j];
#pragma unroll
        for (int off = 32; off > 0; off >>= 1)
            v += __shfl_down(v, off, 64);
        if ((t & 63) == 0) red[t >> 6] = v;
    }
    __syncthreads();
    if (t == 0) scores[k] = red[0] + red[1] + b2[0];
}

// ---------------- Kernel 2: softmax (in-block) + weighted fuse ----------------
// out[d] = 0.5*global[d] + 0.5*sum_k w[k]*client[k][d], float4-vectorized.
// First PF row-loads are issued into registers BEFORE the softmax so HBM
// latency hides under it; out is stored nontemporally (never re-read).
__global__ void lf_fuse_kernel(const float* __restrict__ client,
                               const float* __restrict__ globalt,
                               const float* __restrict__ scores,
                               float* __restrict__ out,
                               int D4) {
    __shared__ float w[KCLIENTS];
    const int t = threadIdx.x;
    const int d = blockIdx.x * BLOCK + t;
    const bool active = (d < D4);

    const float4* __restrict__ c4 = (const float4*)client;
    const float4* __restrict__ g4 = (const float4*)globalt;
    vfloat4* __restrict__ o4 = (vfloat4*)out;

    // issue first PF row loads (independent of weights)
    float4 pre[PF];
    if (active) {
#pragma unroll
        for (int k = 0; k < PF; ++k)
            pre[k] = c4[(size_t)k * D4 + d];
    }

    // wave 0: softmax over the 64 scores (L2-hot) while loads are in flight
    if (t < KCLIENTS) {
        float s = scores[t];
        float m = s;
#pragma unroll
        for (int off = 32; off > 0; off >>= 1)
            m = fmaxf(m, __shfl_xor(m, off, 64));
        float e = __expf(s - m);
        float sum = e;
#pragma unroll
        for (int off = 32; off > 0; off >>= 1)
            sum += __shfl_xor(sum, off, 64);
        w[t] = e / sum;
    }
    __syncthreads();

    if (active) {
        float4 acc = make_float4(0.f, 0.f, 0.f, 0.f);
#pragma unroll
        for (int k = 0; k < PF; ++k) {
            const float wk = w[k];
            acc.x = fmaf(wk, pre[k].x, acc.x);
            acc.y = fmaf(wk, pre[k].y, acc.y);
            acc.z = fmaf(wk, pre[k].z, acc.z);
            acc.w = fmaf(wk, pre[k].w, acc.w);
        }
#pragma unroll 8
        for (int k = PF; k < KCLIENTS; ++k) {
            const float wk = w[k];
            const float4 c = c4[(size_t)k * D4 + d];
            acc.x = fmaf(wk, c.x, acc.x);
            acc.y = fmaf(wk, c.y, acc.y);
            acc.z = fmaf(wk, c.z, acc.z);
            acc.w = fmaf(wk, c.w, acc.w);
        }
        const float4 g = g4[d];
        vfloat4 r;
        r.x = 0.5f * g.x + 0.5f * acc.x;
        r.y = 0.5f * g.y + 0.5f * acc.y;
        r.z = 0.5f * g.z + 0.5f * acc.z;
        r.w = 0.5f * g.w + 0.5f * acc.w;
        __builtin_nontemporal_store(r, &o4[d]);
    }
}

extern "C" void kernel_launch(void* const* d_in, const int* in_sizes, int n_in,
                              void* d_out, int out_size, void* d_ws, size_t ws_size,
                              hipStream_t stream) {
    const float* client  = (const float*)d_in[0];  // [64, D]
    const float* globalt = (const float*)d_in[1];  // [1, D]
    const float* W1      = (const float*)d_in[2];  // [512, 128]
    const float* b1      = (const float*)d_in[3];  // [128]
    const float* W2      = (const float*)d_in[4];  // [128, 1]
    const float* b2      = (const float*)d_in[5];  // [1]
    float* out = (float*)d_out;                    // [1, D]

    const int D  = in_sizes[0] / KCLIENTS;         // 1,000,000
    const int D4 = D / 4;                          // 250,000

    float* scores = (float*)d_ws;                  // 64 floats

    lf_scores_kernel<<<KCLIENTS, 1024, 0, stream>>>(client, globalt, W1, b1, W2, b2,
                                                    scores, D);

    const int grid = (D4 + BLOCK - 1) / BLOCK;     // 977
    lf_fuse_kernel<<<grid, BLOCK, 0, stream>>>(client, globalt, scores, out, D4);
}